// Round 1
// 208.664 us; speedup vs baseline: 1.0006x; 1.0006x over previous
//
#include <hip/hip_runtime.h>
#include <hip/hip_bf16.h>
#include <math.h>

#define B_  16
#define N_  16
#define T_  48
#define C_  512
#define H_  8
#define HD_ 64
#define L_  768
#define BL_ 12288

typedef __attribute__((ext_vector_type(8))) short b16x8;
typedef __attribute__((ext_vector_type(4))) float f32x4;
typedef __attribute__((ext_vector_type(2))) unsigned int u32x2;

__device__ __forceinline__ short f2b(float f) {
  __hip_bfloat16 h = __float2bfloat16(f);
  return *reinterpret_cast<short*>(&h);
}
// fast RNE float->bf16 (no NaN handling; inputs finite)
__device__ __forceinline__ short brne(float f) {
  unsigned u = __float_as_uint(f);
  u += 0x7fffu + ((u >> 16) & 1u);
  return (short)(u >> 16);
}
// packed f32x2 -> bf16x2 (RNE), single VALU op
__device__ __forceinline__ unsigned cvt_pk_bf16(float a, float b) {
  unsigned d;
  asm("v_cvt_pk_bf16_f32 %0, %1, %2" : "=v"(d) : "v"(a), "v"(b));
  return d;
}

// ---------------------------------------------------------------------------
// prep: blocks [0,3072) cast x fp32->bf16; blocks [3072,4096) cast+transpose
// weights into WT[mat][n][k] (Wq pre-scaled by 1/8).
// ---------------------------------------------------------------------------
__global__ __launch_bounds__(256) void prep_kernel(
    const float* __restrict__ x,
    const float* __restrict__ Wq, const float* __restrict__ Wk,
    const float* __restrict__ Wv, const float* __restrict__ Wo,
    short* __restrict__ xb, short* __restrict__ WT)
{
  __shared__ float tile[32][33];
  int blk = blockIdx.x;
  int tid = threadIdx.x;
  if (blk < 3072) {
    int i = blk * 256 + tid;
    const float4* src = (const float4*)(x + (size_t)i * 8);
    float4 a = src[0], b = src[1];
    short tmp[8] = {f2b(a.x), f2b(a.y), f2b(a.z), f2b(a.w),
                    f2b(b.x), f2b(b.y), f2b(b.z), f2b(b.w)};
    *(b16x8*)(xb + (size_t)i * 8) = *(b16x8*)tmp;
  } else {
    int idx = blk - 3072;
    int mat = idx >> 8, rem = idx & 255;
    const float* W = (mat == 0) ? Wq : (mat == 1) ? Wk : (mat == 2) ? Wv : Wo;
    float scale = (mat == 0) ? 0.125f : 1.0f;
    int k0 = (rem >> 4) * 32, n0 = (rem & 15) * 32;
    int tx = tid & 31, ty = tid >> 5;
    for (int i = ty; i < 32; i += 8) tile[i][tx] = W[(size_t)(k0 + i) * 512 + n0 + tx];
    __syncthreads();
    short* dst = WT + (size_t)mat * 262144;
    for (int i = ty; i < 32; i += 8)
      dst[(size_t)(n0 + i) * 512 + k0 + tx] = f2b(tile[tx][i] * scale);
  }
}

// ---------------------------------------------------------------------------
// QKV GEMM, time-major permuted M-rows (rr = pt*16+pn) + LDS-staged epilogue.
//   q2,k2: [b][h][t][n][d]   vT2: [b][h][d][t][n]
// ---------------------------------------------------------------------------
__global__ __launch_bounds__(256) void qkv_kernel(
    const short* __restrict__ xb, const short* __restrict__ WT,
    short* __restrict__ q2, short* __restrict__ k2, short* __restrict__ vT2)
{
  __shared__ short smem[8192];              // As/Bs during K-loop; Ls in epilogue
  short (*As)[32] = (short(*)[32])smem;
  short (*Bs)[32] = (short(*)[32])(smem + 4096);
  int tid = threadIdx.x;
  int w = tid >> 6, lane = tid & 63, n16 = lane & 15, quad = lane >> 4;
  int bm = blockIdx.x, bn = blockIdx.y;
  int mat = bn >> 2;
  int ncol0 = (bn & 3) * 128;
  const short* Wt = WT + (size_t)mat * 262144;
  int bq = bm / 6;
  int rr0 = (bm % 6) * 128;

  f32x4 zero4 = {0.f, 0.f, 0.f, 0.f};
  f32x4 acc[4][4];
  #pragma unroll
  for (int mt = 0; mt < 4; ++mt)
    #pragma unroll
    for (int nt = 0; nt < 4; ++nt) acc[mt][nt] = zero4;

  int srow = tid >> 1, sch = (tid & 1) * 16;
  int rr = rr0 + srow;
  int pt = rr >> 4, pn = rr & 15;           // permuted row -> l = pn*48+pt
  const short* ga = xb + ((size_t)bq * 768 + pn * 48 + pt) * 512 + sch;
  const short* gb = Wt + (size_t)(ncol0 + srow) * 512 + sch;
  int wm = (w >> 1) * 64, wn = (w & 1) * 64;

  for (int kt = 0; kt < 16; ++kt) {
    b16x8 a0 = *(const b16x8*)(ga);
    b16x8 a1 = *(const b16x8*)(ga + 8);
    b16x8 b0 = *(const b16x8*)(gb);
    b16x8 b1 = *(const b16x8*)(gb + 8);
    ga += 32; gb += 32;
    __syncthreads();
    *(b16x8*)&As[srow][sch]     = a0;
    *(b16x8*)&As[srow][sch + 8] = a1;
    *(b16x8*)&Bs[srow][sch]     = b0;
    *(b16x8*)&Bs[srow][sch + 8] = b1;
    __syncthreads();
    b16x8 af[4], bf[4];
    #pragma unroll
    for (int mt = 0; mt < 4; ++mt) af[mt] = *(const b16x8*)&As[wm + mt * 16 + n16][quad * 8];
    #pragma unroll
    for (int nt = 0; nt < 4; ++nt) bf[nt] = *(const b16x8*)&Bs[wn + nt * 16 + n16][quad * 8];
    #pragma unroll
    for (int mt = 0; mt < 4; ++mt)
      #pragma unroll
      for (int nt = 0; nt < 4; ++nt)
        acc[mt][nt] = __builtin_amdgcn_mfma_f32_16x16x32_bf16(af[mt], bf[nt], acc[mt][nt], 0, 0, 0);
  }

  // epilogue: 4 chunks of 32 tile-rows staged through LDS, vector stores out
  short (*Ls)[136] = (short(*)[136])smem;   // 32 x 136 (pad: aligned, spread banks)
  for (int c = 0; c < 4; ++c) {
    __syncthreads();
    if ((w >> 1) == (c >> 1)) {             // waves owning rows 32c..32c+31
      int mtb = (c & 1) * 2;
      #pragma unroll
      for (int mi = 0; mi < 2; ++mi) {
        #pragma unroll
        for (int nt = 0; nt < 4; ++nt)
          #pragma unroll
          for (int r = 0; r < 4; ++r)
            Ls[mi * 16 + quad * 4 + r][wn + nt * 16 + n16] = f2b(acc[mtb + mi][nt][r]);
      }
    }
    __syncthreads();
    int rrc = rr0 + c * 32;
    if (mat != 2) {
      short* dst = (mat == 0) ? q2 : k2;
      int row = tid >> 3, c0 = (tid & 7) * 16;
      int hhg = (ncol0 + c0) >> 6, d0 = (ncol0 + c0) & 63;
      short* dp = dst + ((size_t)(bq * 8 + hhg) * 768 + rrc + row) * 64 + d0;
      *(b16x8*)dp       = *(b16x8*)&Ls[row][c0];
      *(b16x8*)(dp + 8) = *(b16x8*)&Ls[row][c0 + 8];
    } else {
      int cp = tid & 63, r8 = (tid >> 6) * 8;
      int c0 = 2 * cp;
      int hhg = (ncol0 + c0) >> 6, d0 = (ncol0 + c0) & 63;
      short t0[8], t1[8];
      #pragma unroll
      for (int j = 0; j < 8; ++j) { t0[j] = Ls[r8 + j][c0]; t1[j] = Ls[r8 + j][c0 + 1]; }
      short* dp = vT2 + ((size_t)(bq * 8 + hhg) * 64 + d0) * 768 + rrc + r8;
      *(b16x8*)dp         = *(b16x8*)t0;
      *(b16x8*)(dp + 768) = *(b16x8*)t1;
    }
  }
}

// ---------------------------------------------------------------------------
// Attention (R6 core): SWAPPED QK^T (S^T = K x Q) so each lane owns one q-row;
// P goes to the PV A-fragment via cvt_pk_bf16 + permlane{32,16}_swap — the
// LDS P round-trip (32 ds_write_b16 + ds_read_b128 + lgkm drain per step) is
// GONE. Time-bias is wave-uniform per tile. V rotated into the K prefetch
// double-buffer. Softmax denom is a per-lane scalar, reduced once at the end.
// ---------------------------------------------------------------------------
__global__ __launch_bounds__(128, 3) void attn_kernel(
    const short* __restrict__ q2, const short* __restrict__ k2,
    const short* __restrict__ vT2,
    const float* __restrict__ relT, const float* __restrict__ relP,
    short* __restrict__ yatt)
{
  __shared__ float btL[2][96];

  int tid = threadIdx.x;
  int wv = tid >> 6, lane = tid & 63, n16 = lane & 15, quad = lane >> 4;
  int blk = blockIdx.x;
  int h = blk & 7;                          // XCD-locality
  int g = blk >> 3;
  int pg = g % 12, b = g / 12;
  int pair = pg * 2 + wv;
  int qtA = pair, qtB = 47 - pair;
  int nA = (qtA + 2) >> 1, nB = (qtB + 2) >> 1;

  btL[wv][lane] = relT[(lane < 95 ? lane : 94) * 8 + h];
  if (lane < 32) btL[wv][64 + lane] = relT[((64 + lane) < 95 ? 64 + lane : 94) * 8 + h];

  // swapped layout: reg r = key particle quad*4+r, lane n16 = q particle
  // bias_p[q][k] = relP[k - q + 15]
  float bpT[4];
  #pragma unroll
  for (int r = 0; r < 4; ++r)
    bpT[r] = relP[(quad * 4 + r - n16 + 15) * 8 + h];

  size_t bh = (size_t)(b * 8 + h);
  const short* qb = q2 + bh * 49152;
  const short* kb = k2 + bh * 49152;
  const short* vb = vT2 + bh * 49152;

  b16x8 qA0 = *(const b16x8*)(qb + (qtA * 16 + n16) * 64 + quad * 8);
  b16x8 qA1 = *(const b16x8*)(qb + (qtA * 16 + n16) * 64 + quad * 8 + 32);
  b16x8 qB0 = *(const b16x8*)(qb + (qtB * 16 + n16) * 64 + quad * 8);
  b16x8 qB1 = *(const b16x8*)(qb + (qtB * 16 + n16) * 64 + quad * 8 + 32);

  f32x4 zero4 = {0.f, 0.f, 0.f, 0.f};
  f32x4 oA[4], oB[4];
  float psA = 0.f, psB = 0.f;
  #pragma unroll
  for (int nt = 0; nt < 4; ++nt) { oA[nt] = zero4; oB[nt] = zero4; }

  b16x8 kfa[4], kfb[4], vfa[4], vfb[4];
  auto loadKV = [&](int kt2, b16x8* kf, b16x8* vf) {
    const short* kp = kb + (size_t)(kt2 * 32 + n16) * 64 + quad * 8;
    kf[0] = *(const b16x8*)kp;
    kf[1] = *(const b16x8*)(kp + 32);
    kf[2] = *(const b16x8*)(kp + 1024);
    kf[3] = *(const b16x8*)(kp + 1024 + 32);
    const short* vp = vb + (size_t)n16 * 768 + kt2 * 32 + quad * 8;
    vf[0] = *(const b16x8*)vp;
    vf[1] = *(const b16x8*)(vp + 16 * 768);
    vf[2] = *(const b16x8*)(vp + 32 * 768);
    vf[3] = *(const b16x8*)(vp + 48 * 768);
  };

  // exp+bias on S^T tile pair, pack to the PV A-fragment in-register.
  // Input: s0 = keys(time kt0, particles 4q..4q+3), s1 = time kt0+1.
  // Output fragment word w at quad qt = keys (8qt+2w, 8qt+2w+1),
  // key index = tloc*16 + particle (matches vT2 column order).
  auto exp_pack = [&](const f32x4& s0, const f32x4& s1, float bt0, float bt1,
                      float& ps) -> b16x8 {
    float e00 = __expf(s0[0] + bt0 + bpT[0]);
    float e01 = __expf(s0[1] + bt0 + bpT[1]);
    float e02 = __expf(s0[2] + bt0 + bpT[2]);
    float e03 = __expf(s0[3] + bt0 + bpT[3]);
    float e10 = __expf(s1[0] + bt1 + bpT[0]);
    float e11 = __expf(s1[1] + bt1 + bpT[1]);
    float e12 = __expf(s1[2] + bt1 + bpT[2]);
    float e13 = __expf(s1[3] + bt1 + bpT[3]);
    ps += ((e00 + e01) + (e02 + e03)) + ((e10 + e11) + (e12 + e13));
    unsigned p0 = cvt_pk_bf16(e00, e01);    // particles 4q+0,1  @ t0
    unsigned p1 = cvt_pk_bf16(e02, e03);    // particles 4q+2,3  @ t0
    unsigned p2 = cvt_pk_bf16(e10, e11);    // particles 4q+0,1  @ t1
    unsigned p3 = cvt_pk_bf16(e12, e13);    // particles 4q+2,3  @ t1
    u32x2 a02 = __builtin_amdgcn_permlane32_swap(p0, p2, false, false);
    u32x2 z02 = __builtin_amdgcn_permlane16_swap(a02.x, a02.y, false, false);
    u32x2 a13 = __builtin_amdgcn_permlane32_swap(p1, p3, false, false);
    u32x2 z13 = __builtin_amdgcn_permlane16_swap(a13.x, a13.y, false, false);
    union { unsigned u[4]; b16x8 v; } r;
    r.u[0] = z02.x;                         // keys 8qt+0,1
    r.u[1] = z13.x;                         // keys 8qt+2,3
    r.u[2] = z02.y;                         // keys 8qt+4,5
    r.u[3] = z13.y;                         // keys 8qt+6,7
    return r.v;
  };

  auto step = [&](int kt2, const b16x8* kf, const b16x8* vf) {
    int kt0 = kt2 * 2;
    bool doA = kt2 < nA;                    // wave-uniform
    // swapped QK^T: S^T[key][q] — lane&15 = q, rows = key particle
    f32x4 sB0 = zero4, sB1 = zero4;
    sB0 = __builtin_amdgcn_mfma_f32_16x16x32_bf16(kf[0], qB0, sB0, 0, 0, 0);
    sB0 = __builtin_amdgcn_mfma_f32_16x16x32_bf16(kf[1], qB1, sB0, 0, 0, 0);
    sB1 = __builtin_amdgcn_mfma_f32_16x16x32_bf16(kf[2], qB0, sB1, 0, 0, 0);
    sB1 = __builtin_amdgcn_mfma_f32_16x16x32_bf16(kf[3], qB1, sB1, 0, 0, 0);
    f32x4 sA0 = zero4, sA1 = zero4;
    if (doA) {
      sA0 = __builtin_amdgcn_mfma_f32_16x16x32_bf16(kf[0], qA0, sA0, 0, 0, 0);
      sA0 = __builtin_amdgcn_mfma_f32_16x16x32_bf16(kf[1], qA1, sA0, 0, 0, 0);
      sA1 = __builtin_amdgcn_mfma_f32_16x16x32_bf16(kf[2], qA0, sA1, 0, 0, 0);
      sA1 = __builtin_amdgcn_mfma_f32_16x16x32_bf16(kf[3], qA1, sA1, 0, 0, 0);
    }
    float btB0 = (kt0 <= qtB) ? btL[wv][kt0 - qtB + 47] : -1e30f;     // uniform
    float btB1 = (kt0 + 1 <= qtB) ? btL[wv][kt0 + 1 - qtB + 47] : -1e30f;
    b16x8 pfB = exp_pack(sB0, sB1, btB0, btB1, psB);
    #pragma unroll
    for (int nt = 0; nt < 4; ++nt)
      oB[nt] = __builtin_amdgcn_mfma_f32_16x16x32_bf16(pfB, vf[nt], oB[nt], 0, 0, 0);
    if (doA) {
      float btA0 = (kt0 <= qtA) ? btL[wv][kt0 - qtA + 47] : -1e30f;
      float btA1 = (kt0 + 1 <= qtA) ? btL[wv][kt0 + 1 - qtA + 47] : -1e30f;
      b16x8 pfA = exp_pack(sA0, sA1, btA0, btA1, psA);
      #pragma unroll
      for (int nt = 0; nt < 4; ++nt)
        oA[nt] = __builtin_amdgcn_mfma_f32_16x16x32_bf16(pfA, vf[nt], oA[nt], 0, 0, 0);
    }
  };

  loadKV(0, kfa, vfa);
  for (int kt2 = 0; kt2 < nB; kt2 += 2) {
    if (kt2 + 1 < nB) loadKV(kt2 + 1, kfb, vfb);
    step(kt2, kfa, vfa);
    if (kt2 + 1 < nB) {
      if (kt2 + 2 < nB) loadKV(kt2 + 2, kfa, vfa);
      step(kt2 + 1, kfb, vfb);
    }
  }

  // denom: per-lane partial (q = n16, keys split across quads) -> full sum
  psA += __shfl_xor(psA, 16); psA += __shfl_xor(psA, 32);
  psB += __shfl_xor(psB, 16); psB += __shfl_xor(psB, 32);
  float invA = 1.0f / psA, invB = 1.0f / psB;
  // redistribute to C-layout rows: lane needs 1/ps for q = quad*4+r
  float pnA[4], pnB[4];
  #pragma unroll
  for (int r = 0; r < 4; ++r) {
    pnA[r] = __shfl(invA, quad * 4 + r);
    pnB[r] = __shfl(invB, quad * 4 + r);
  }

  #pragma unroll
  for (int nt = 0; nt < 4; ++nt) {
    int c = h * 64 + nt * 16 + n16;
    #pragma unroll
    for (int r = 0; r < 4; ++r) {
      int qn = quad * 4 + r;
      yatt[((size_t)b * 768 + qn * 48 + qtA) * 512 + c] = f2b(oA[nt][r] * pnA[r]);
      yatt[((size_t)b * 768 + qn * 48 + qtB) * 512 + c] = f2b(oB[nt][r] * pnB[r]);
    }
  }
}

// ---------------------------------------------------------------------------
// proj: yatt(12288x512,bf16) @ WoT -> out fp32
// ---------------------------------------------------------------------------
__global__ __launch_bounds__(256) void proj_kernel(
    const short* __restrict__ yatt, const short* __restrict__ WT,
    float* __restrict__ out)
{
  __shared__ short As[128][32];
  __shared__ short Bs[128][32];
  int tid = threadIdx.x;
  int w = tid >> 6, lane = tid & 63, n16 = lane & 15, quad = lane >> 4;
  int row0 = blockIdx.x * 128;
  int ncol0 = blockIdx.y * 128;
  const short* Wt = WT + (size_t)3 * 262144;

  f32x4 zero4 = {0.f, 0.f, 0.f, 0.f};
  f32x4 acc[4][4];
  #pragma unroll
  for (int mt = 0; mt < 4; ++mt)
    #pragma unroll
    for (int nt = 0; nt < 4; ++nt) acc[mt][nt] = zero4;

  int srow = tid >> 1, sch = (tid & 1) * 16;
  const short* ga = yatt + (size_t)(row0 + srow) * 512 + sch;
  const short* gb = Wt + (size_t)(ncol0 + srow) * 512 + sch;
  int wm = (w >> 1) * 64, wn = (w & 1) * 64;

  for (int kt = 0; kt < 16; ++kt) {
    b16x8 a0 = *(const b16x8*)(ga);
    b16x8 a1 = *(const b16x8*)(ga + 8);
    b16x8 b0 = *(const b16x8*)(gb);
    b16x8 b1 = *(const b16x8*)(gb + 8);
    ga += 32; gb += 32;
    __syncthreads();
    *(b16x8*)&As[srow][sch]     = a0;
    *(b16x8*)&As[srow][sch + 8] = a1;
    *(b16x8*)&Bs[srow][sch]     = b0;
    *(b16x8*)&Bs[srow][sch + 8] = b1;
    __syncthreads();
    b16x8 af[4], bf[4];
    #pragma unroll
    for (int mt = 0; mt < 4; ++mt) af[mt] = *(const b16x8*)&As[wm + mt * 16 + n16][quad * 8];
    #pragma unroll
    for (int nt = 0; nt < 4; ++nt) bf[nt] = *(const b16x8*)&Bs[wn + nt * 16 + n16][quad * 8];
    #pragma unroll
    for (int mt = 0; mt < 4; ++mt)
      #pragma unroll
      for (int nt = 0; nt < 4; ++nt)
        acc[mt][nt] = __builtin_amdgcn_mfma_f32_16x16x32_bf16(af[mt], bf[nt], acc[mt][nt], 0, 0, 0);
  }

  #pragma unroll
  for (int mt = 0; mt < 4; ++mt) {
    int rowb = row0 + wm + mt * 16 + quad * 4;
    #pragma unroll
    for (int nt = 0; nt < 4; ++nt) {
      int colg = ncol0 + wn + nt * 16 + n16;
      #pragma unroll
      for (int r = 0; r < 4; ++r)
        out[(size_t)(rowb + r) * 512 + colg] = acc[mt][nt][r];
    }
  }
}

// ---------------------------------------------------------------------------
extern "C" void kernel_launch(void* const* d_in, const int* in_sizes, int n_in,
                              void* d_out, int out_size, void* d_ws, size_t ws_size,
                              hipStream_t stream) {
  const float* x    = (const float*)d_in[0];
  const float* Wq   = (const float*)d_in[1];
  const float* Wk   = (const float*)d_in[2];
  const float* Wv   = (const float*)d_in[3];
  const float* Wo   = (const float*)d_in[4];
  const float* relT = (const float*)d_in[5];
  const float* relP = (const float*)d_in[6];

  char* wsb = (char*)d_ws;
  const size_t SZ = (size_t)BL_ * C_ * 2;
  short* xb  = (short*)(wsb);
  short* WT  = (short*)(wsb + SZ);
  short* qb  = (short*)(wsb + SZ + 2097152);
  short* kb  = (short*)(wsb + 2 * SZ + 2097152);
  short* vTb = (short*)(wsb + 3 * SZ + 2097152);
  short* yat = (short*)(wsb + 4 * SZ + 2097152 + 4096);

  prep_kernel<<<dim3(4096), dim3(256), 0, stream>>>(x, Wq, Wk, Wv, Wo, xb, WT);
  qkv_kernel<<<dim3(96, 12), dim3(256), 0, stream>>>(xb, WT, qb, kb, vTb);
  attn_kernel<<<dim3(1536), dim3(128), 0, stream>>>(qb, kb, vTb, relT, relP, yat);
  proj_kernel<<<dim3(96, 4), dim3(256), 0, stream>>>(yat, WT, (float*)d_out);
}